// Round 1
// baseline (973.448 us; speedup 1.0000x reference)
//
#include <hip/hip_runtime.h>
#include <hip/hip_bf16.h>

typedef __bf16 bf16x8 __attribute__((ext_vector_type(8)));
typedef float  f32x4  __attribute__((ext_vector_type(4)));

#define MFMA16(a, b, c) __builtin_amdgcn_mfma_f32_16x16x32_bf16((a), (b), (c), 0, 0, 0)

// Convert fp32 weights -> bf16 copies in workspace (re-done every launch; no
// static state). Layouts stay n-major ([out][in]) so each lane's 8 k-elements
// for a B-fragment are 16 contiguous bytes.
__global__ void prep_weights(const float* __restrict__ W1, const float* __restrict__ W2,
                             const float* __restrict__ Wf1, const float* __restrict__ Wf2,
                             __bf16* __restrict__ w1b, __bf16* __restrict__ w2b,
                             __bf16* __restrict__ wf1b, __bf16* __restrict__ wf2b) {
    int i = blockIdx.x * 256 + threadIdx.x;
    if (i < 256 * 512) w1b[i]  = (__bf16)W1[i];
    if (i < 128 * 256) w2b[i]  = (__bf16)W2[i];
    if (i < 64 * 128)  wf1b[i] = (__bf16)Wf1[i];
    if (i < 2 * 64)    wf2b[i] = (__bf16)Wf2[i];
}

// One wave owns 32 rows through the whole MLP. No __syncthreads anywhere:
// the LDS h-buffer is wave-private (reused for h1 -> h2 -> h3).
// MFMA 16x16x32 bf16 layouts (guide-verified):
//   A[m = lane&15][k = (lane>>4)*8 + j]     (8 bf16 / lane, contiguous in k)
//   B[k = (lane>>4)*8 + j][n = lane&15]     (n-major weight rows -> 16B/lane)
//   C/D: col = lane&15, row = (lane>>4)*4 + reg
__global__ __launch_bounds__(128, 2)
void mlp_kernel(const float* __restrict__ X,
                const __bf16* __restrict__ w1b,  const float* __restrict__ b1,
                const __bf16* __restrict__ w2b,  const float* __restrict__ b2,
                const __bf16* __restrict__ wf1b, const float* __restrict__ bf1,
                const __bf16* __restrict__ wf2b, const float* __restrict__ bf2,
                float* __restrict__ out) {
    // 264 = 256 + 8 bf16 pad: keeps 16B alignment for b128 reads, row stride
    // 528 B == 4 banks mod 32 -> only free 2-way aliasing.
    __shared__ __align__(16) __bf16 hbuf[2][32][264];

    const int lane = threadIdx.x & 63;
    const int wave = threadIdx.x >> 6;
    const int m16  = lane & 15;
    const int q    = lane >> 4;
    const int row0 = blockIdx.x * 64 + wave * 32;
    __bf16(*hw)[264] = hbuf[wave];

    // ---------------- Layer 1: h1[32,256] = relu(X[32,512] @ W1^T + b1) ----
    f32x4 C1[2][16];
#pragma unroll
    for (int rt = 0; rt < 2; ++rt)
#pragma unroll
        for (int ct = 0; ct < 16; ++ct) C1[rt][ct] = (f32x4){0.f, 0.f, 0.f, 0.f};

    for (int ks = 0; ks < 16; ++ks) {
        const int k0 = ks * 32 + q * 8;
        bf16x8 a[2];
#pragma unroll
        for (int rt = 0; rt < 2; ++rt) {
            const float4* p = (const float4*)(X + (size_t)(row0 + rt * 16 + m16) * 512 + k0);
            float4 f0 = p[0], f1 = p[1];
            a[rt][0] = (__bf16)f0.x; a[rt][1] = (__bf16)f0.y;
            a[rt][2] = (__bf16)f0.z; a[rt][3] = (__bf16)f0.w;
            a[rt][4] = (__bf16)f1.x; a[rt][5] = (__bf16)f1.y;
            a[rt][6] = (__bf16)f1.z; a[rt][7] = (__bf16)f1.w;
        }
#pragma unroll
        for (int ct = 0; ct < 16; ++ct) {
            bf16x8 b = *(const bf16x8*)(w1b + (size_t)(ct * 16 + m16) * 512 + k0);
            C1[0][ct] = MFMA16(a[0], b, C1[0][ct]);
            C1[1][ct] = MFMA16(a[1], b, C1[1][ct]);
        }
    }
#pragma unroll
    for (int ct = 0; ct < 16; ++ct) {
        float bias = b1[ct * 16 + m16];
#pragma unroll
        for (int rt = 0; rt < 2; ++rt)
#pragma unroll
            for (int r = 0; r < 4; ++r) {
                float v = C1[rt][ct][r] + bias;
                v = v > 0.f ? v : 0.f;
                hw[rt * 16 + q * 4 + r][ct * 16 + m16] = (__bf16)v;
            }
    }

    // ---------------- Layer 2: h2[32,128] = relu(h1 @ W2^T + b2) -----------
    f32x4 C2[2][8];
#pragma unroll
    for (int rt = 0; rt < 2; ++rt)
#pragma unroll
        for (int ct = 0; ct < 8; ++ct) C2[rt][ct] = (f32x4){0.f, 0.f, 0.f, 0.f};

    for (int ks = 0; ks < 8; ++ks) {
        const int k0 = ks * 32 + q * 8;
        bf16x8 a[2];
#pragma unroll
        for (int rt = 0; rt < 2; ++rt)
            a[rt] = *(const bf16x8*)&hw[rt * 16 + m16][k0];
#pragma unroll
        for (int ct = 0; ct < 8; ++ct) {
            bf16x8 b = *(const bf16x8*)(w2b + (size_t)(ct * 16 + m16) * 256 + k0);
            C2[0][ct] = MFMA16(a[0], b, C2[0][ct]);
            C2[1][ct] = MFMA16(a[1], b, C2[1][ct]);
        }
    }
#pragma unroll
    for (int ct = 0; ct < 8; ++ct) {
        float bias = b2[ct * 16 + m16];
#pragma unroll
        for (int rt = 0; rt < 2; ++rt)
#pragma unroll
            for (int r = 0; r < 4; ++r) {
                float v = C2[rt][ct][r] + bias;
                v = v > 0.f ? v : 0.f;
                hw[rt * 16 + q * 4 + r][ct * 16 + m16] = (__bf16)v;
            }
    }

    // ---------------- Layer 3: h3[32,64] = relu(h2 @ Wf1^T + bf1) ----------
    f32x4 C3[2][4];
#pragma unroll
    for (int rt = 0; rt < 2; ++rt)
#pragma unroll
        for (int ct = 0; ct < 4; ++ct) C3[rt][ct] = (f32x4){0.f, 0.f, 0.f, 0.f};

    for (int ks = 0; ks < 4; ++ks) {
        const int k0 = ks * 32 + q * 8;
        bf16x8 a[2];
#pragma unroll
        for (int rt = 0; rt < 2; ++rt)
            a[rt] = *(const bf16x8*)&hw[rt * 16 + m16][k0];
#pragma unroll
        for (int ct = 0; ct < 4; ++ct) {
            bf16x8 b = *(const bf16x8*)(wf1b + (size_t)(ct * 16 + m16) * 128 + k0);
            C3[0][ct] = MFMA16(a[0], b, C3[0][ct]);
            C3[1][ct] = MFMA16(a[1], b, C3[1][ct]);
        }
    }
#pragma unroll
    for (int ct = 0; ct < 4; ++ct) {
        float bias = bf1[ct * 16 + m16];
#pragma unroll
        for (int rt = 0; rt < 2; ++rt)
#pragma unroll
            for (int r = 0; r < 4; ++r) {
                float v = C3[rt][ct][r] + bias;
                v = v > 0.f ? v : 0.f;
                hw[rt * 16 + q * 4 + r][ct * 16 + m16] = (__bf16)v;
            }
    }

    // ---------------- Layer 4 + softmax (fp32): lane -> (row, class) -------
    {
        const int r = lane >> 1;
        const int c = lane & 1;
        float dot = 0.f;
#pragma unroll
        for (int j8 = 0; j8 < 8; ++j8) {
            bf16x8 hv = *(const bf16x8*)&hw[r][j8 * 8];
            bf16x8 wv = *(const bf16x8*)(wf2b + c * 64 + j8 * 8);
#pragma unroll
            for (int j = 0; j < 8; ++j) dot += (float)hv[j] * (float)wv[j];
        }
        float logit = dot + bf2[c];
        float other = __shfl_xor(logit, 1, 64);
        float mx = fmaxf(logit, other);
        float e0 = expf(logit - mx);
        float e1 = expf(other - mx);
        out[(size_t)(row0 + r) * 2 + c] = e0 / (e0 + e1);
    }
}

extern "C" void kernel_launch(void* const* d_in, const int* in_sizes, int n_in,
                              void* d_out, int out_size, void* d_ws, size_t ws_size,
                              hipStream_t stream) {
    const float* X   = (const float*)d_in[0];
    const float* W1  = (const float*)d_in[1];
    const float* b1  = (const float*)d_in[2];
    const float* W2  = (const float*)d_in[3];
    const float* b2  = (const float*)d_in[4];
    const float* Wf1 = (const float*)d_in[5];
    const float* bf1 = (const float*)d_in[6];
    const float* Wf2 = (const float*)d_in[7];
    const float* bf2 = (const float*)d_in[8];
    float* out = (float*)d_out;

    const int N = in_sizes[0] / 512;  // 262144

    __bf16* w1b  = (__bf16*)d_ws;           // 256*512
    __bf16* w2b  = w1b + 256 * 512;         // 128*256
    __bf16* wf1b = w2b + 128 * 256;         // 64*128
    __bf16* wf2b = wf1b + 64 * 128;         // 2*64

    prep_weights<<<512, 256, 0, stream>>>(W1, W2, Wf1, Wf2, w1b, w2b, wf1b, wf2b);
    mlp_kernel<<<N / 64, 128, 0, stream>>>(X, w1b, b1, w2b, b2, wf1b, bf1,
                                           wf2b, bf2, out);
}